// Round 3
// baseline (587.714 us; speedup 1.0000x reference)
//
#include <hip/hip_runtime.h>

// Problem constants
#define BB 4
#define NN 16384
#define EGc 131072
#define CAP 64
#define INVSQ 0.17677669529663687f

typedef unsigned int uint;
typedef unsigned short ushort;
typedef short short8 __attribute__((ext_vector_type(8)));    // 8 bf16 = 4 VGPR (MFMA A/B frag)
typedef float floatx4 __attribute__((ext_vector_type(4)));   // MFMA C/D frag

__device__ __forceinline__ float bflo(uint u) { return __uint_as_float(u << 16); }
__device__ __forceinline__ float bfhi(uint u) { return __uint_as_float(u & 0xffff0000u); }
__device__ __forceinline__ ushort f2bf(float f) {
    uint u = __float_as_uint(f);
    u += 0x7fffu + ((u >> 16) & 1u);   // RTNE
    return (ushort)(u >> 16);
}

#define SA_STRIDE 136
#define SW_STRIDE 136
#define SY_STRIDE 132
struct __align__(16) SMem {
    union {
        struct {
            ushort sA[64 * SA_STRIDE];    // 17408 B
            ushort sW[128 * SW_STRIDE];   // 34816 B
        };
        float  sY[64 * SY_STRIDE];        // 33792 B
        ushort sOut[64 * 128];            // 16384 B (proj bf16 out-stage)
    };
};

// ---- staging: X rows (f32 -> bf16, row-major) ----
__device__ __forceinline__ void stage_x(SMem& sm, const float4* __restrict__ X4,
                                        size_t r0, int t) {
#pragma unroll
    for (int i = 0; i < 8; ++i) {
        int f = t + 256 * i;              // 2048 float4 = 64 rows x 32
        int r = f >> 5, c4 = f & 31;
        float4 x = X4[(r0 + r) * 32 + c4];
        ushort4 h;
        h.x = f2bf(x.x); h.y = f2bf(x.y); h.z = f2bf(x.z); h.w = f2bf(x.w);
        *(ushort4*)&sm.sA[r * SA_STRIDE + c4 * 4] = h;
    }
}

// ---- staging: pre-transposed bf16 weight (global [128 cols][128 k]) -> LDS padded ----
__device__ __forceinline__ void stage_wt(SMem& sm, const uint4* __restrict__ Wt4, int t) {
#pragma unroll
    for (int i = 0; i < 8; ++i) {
        int f = t + 256 * i;              // 2048 uint4; c = row, kc = 8-elt chunk
        int c = f >> 4, kc = f & 15;
        uint4 w = Wt4[f];
        *(uint4*)&sm.sW[c * SW_STRIDE + kc * 8] = w;
    }
}

// ---- MFMA core: 64x128 tile, K=128. Wave = 32 rows x 64 cols (2x4 16x16 tiles) ----
__device__ __forceinline__ void mfma_core(const SMem& sm, int t, floatx4 (&acc)[2][4]) {
    int lane = t & 63, w = t >> 6;
    int wr = (w >> 1) * 32, wc = (w & 1) * 64;
    int m = lane & 15, q = lane >> 4;
#pragma unroll
    for (int ks = 0; ks < 4; ++ks) {
        int k = ks * 32 + q * 8;
        short8 a0 = *(const short8*)&sm.sA[(wr + m) * SA_STRIDE + k];
        short8 a1 = *(const short8*)&sm.sA[(wr + 16 + m) * SA_STRIDE + k];
#pragma unroll
        for (int j = 0; j < 4; ++j) {
            short8 b = *(const short8*)&sm.sW[(wc + j * 16 + m) * SW_STRIDE + k];
            acc[0][j] = __builtin_amdgcn_mfma_f32_16x16x32_bf16(a0, b, acc[0][j], 0, 0, 0);
            acc[1][j] = __builtin_amdgcn_mfma_f32_16x16x32_bf16(a1, b, acc[1][j], 0, 0, 0);
        }
    }
}

__device__ __forceinline__ void acc_zero(floatx4 (&acc)[2][4]) {
    floatx4 z = {0.f, 0.f, 0.f, 0.f};
#pragma unroll
    for (int i = 0; i < 2; ++i)
#pragma unroll
        for (int j = 0; j < 4; ++j) acc[i][j] = z;
}

// C/D layout: col = lane&15, row = (lane>>4)*4 + reg   [m89-verified]
__device__ __forceinline__ void acc_to_sy(SMem& sm, int t, const floatx4 (&acc)[2][4]) {
    int lane = t & 63, w = t >> 6;
    int wr = (w >> 1) * 32, wc = (w & 1) * 64;
    int m = lane & 15, q = lane >> 4;
#pragma unroll
    for (int i = 0; i < 2; ++i)
#pragma unroll
        for (int j = 0; j < 4; ++j)
#pragma unroll
            for (int r = 0; r < 4; ++r)
                sm.sY[(wr + i * 16 + q * 4 + r) * SY_STRIDE + wc + j * 16 + m] = acc[i][j][r];
}

// ============================ kernel 0: weight pre-transpose ============================
__global__ __launch_bounds__(256) void transpose_w(const float* __restrict__ W0,
                                                   const float* __restrict__ W1,
                                                   const float* __restrict__ W2,
                                                   const float* __restrict__ W3,
                                                   const float* __restrict__ W4,
                                                   ushort* __restrict__ Wt) {
    __shared__ ushort sT[128 * 136];
    int bi = blockIdx.x;
    const float* W = bi == 0 ? W0 : bi == 1 ? W1 : bi == 2 ? W2 : bi == 3 ? W3 : W4;
    int t = threadIdx.x;
    const float4* Wp = (const float4*)W;
#pragma unroll
    for (int i = 0; i < 16; ++i) {
        int f = t + 256 * i;
        int d = f >> 5, c4 = f & 31;
        float4 w = Wp[f];
        sT[(c4 * 4 + 0) * 136 + d] = f2bf(w.x);
        sT[(c4 * 4 + 1) * 136 + d] = f2bf(w.y);
        sT[(c4 * 4 + 2) * 136 + d] = f2bf(w.z);
        sT[(c4 * 4 + 3) * 136 + d] = f2bf(w.w);
    }
    __syncthreads();
    uint4* out = (uint4*)(Wt + (size_t)bi * 16384);
#pragma unroll
    for (int i = 0; i < 8; ++i) {
        int f = t + 256 * i;
        int c = f >> 4, kc = f & 15;
        out[f] = *(const uint4*)&sT[c * 136 + kc * 8];
    }
}

// ============================ kernel 1: fused Q/K/V projection ============================
__global__ __launch_bounds__(256) void proj_mfma(const float* __restrict__ IQ,
                                                 const float* __restrict__ IK,
                                                 const float* __restrict__ IV,
                                                 const ushort* __restrict__ WtAll,
                                                 ushort* __restrict__ Qp,
                                                 ushort* __restrict__ Kp,
                                                 ushort* __restrict__ Vp) {
    __shared__ SMem sm;
    int t = threadIdx.x;
    const float* X; const ushort* Wt; ushort* Y;
    if (blockIdx.y == 0)      { X = IQ; Wt = WtAll;         Y = Qp; }
    else if (blockIdx.y == 1) { X = IK; Wt = WtAll + 16384; Y = Kp; }
    else                      { X = IV; Wt = WtAll + 32768; Y = Vp; }
    size_t r0 = (size_t)blockIdx.x * 64;
    stage_x(sm, (const float4*)X, r0, t);
    stage_wt(sm, (const uint4*)Wt, t);
    __syncthreads();
    floatx4 acc[2][4];
    acc_zero(acc);
    mfma_core(sm, t, acc);
    __syncthreads();
    {
        int lane = t & 63, w = t >> 6;
        int wr = (w >> 1) * 32, wc = (w & 1) * 64;
        int m = lane & 15, q = lane >> 4;
#pragma unroll
        for (int i = 0; i < 2; ++i)
#pragma unroll
            for (int j = 0; j < 4; ++j)
#pragma unroll
                for (int r = 0; r < 4; ++r)
                    sm.sOut[(wr + i * 16 + q * 4 + r) * 128 + wc + j * 16 + m] = f2bf(acc[i][j][r]);
    }
    __syncthreads();
    uint4* Y4 = (uint4*)Y;
#pragma unroll
    for (int i = 0; i < 4; ++i) {
        int f = t + 256 * i;
        Y4[r0 * 16 + f] = *(const uint4*)&sm.sOut[f * 8];
    }
}

// ============================ kernel 2: edges ============================
// E = EF @ W_E (MFMA) + score/exp. av is written slot-ordered into af_buf[node][slot][head]
// so the gather kernel can read it coalesced without the list->aArr dependent hop.
__global__ __launch_bounds__(256, 3) void edge_kernel(const int* __restrict__ EI,
                                                      const float* __restrict__ EF,
                                                      const ushort* __restrict__ WtE,
                                                      const ushort* __restrict__ Qp,
                                                      const ushort* __restrict__ Kp,
                                                      float* __restrict__ af_buf,
                                                      int* __restrict__ list,
                                                      int* __restrict__ cnt,
                                                      float* __restrict__ attn_out) {
    __shared__ SMem sm;
    __shared__ int sSrc[64];
    __shared__ int sSlot[64];
    int t = threadIdx.x;
    int b = blockIdx.x >> 11;            // 2048 tiles per batch
    int tile = blockIdx.x & 2047;
    int e0 = tile * 64;
    int w = t >> 6, lane = t & 63;

    // --- prefetch Q/K rows for this wave's 16 edges FIRST (32 long-pole loads in flight) ---
    int e16 = w * 16 + (lane & 15);
    int srcv = EI[(size_t)b * 2 * EGc + e0 + e16];
    int tgtv = EI[(size_t)b * 2 * EGc + EGc + e0 + e16];
    const uint* Qu = (const uint*)Qp;
    const uint* Ku = (const uint*)Kp;
    uint q01[16], k01[16];
#pragma unroll
    for (int ei = 0; ei < 16; ++ei) {
        int s = __shfl(srcv, ei, 16);
        int g = __shfl(tgtv, ei, 16);
        q01[ei] = Qu[((size_t)b * NN + s) * 64 + lane];
        k01[ei] = Ku[((size_t)b * NN + g) * 64 + lane];
    }

    // --- parallel list append: one thread per edge; payload packs (tgt<<17)|ge ---
    if (t < 64) {
        int ge = e0 + t;
        int src = EI[(size_t)b * 2 * EGc + ge];
        int tgt = EI[(size_t)b * 2 * EGc + EGc + ge];
        int slot = atomicAdd(&cnt[b * NN + src], 1);
        sSrc[t] = src;
        sSlot[t] = slot;
        if (slot < CAP) list[((size_t)(b * NN + src)) * CAP + slot] = (tgt << 17) | ge;
    }

    stage_x(sm, (const float4*)EF, (size_t)b * EGc + e0, t);
    stage_wt(sm, (const uint4*)WtE, t);
    __syncthreads();
    floatx4 acc[2][4];
    acc_zero(acc);
    mfma_core(sm, t, acc);
    __syncthreads();
    acc_to_sy(sm, t, acc);               // sY[e][c] = E values (f32)
    __syncthreads();

    int h = lane >> 4;                   // head of channels 2*lane, 2*lane+1
    bool isLast = (b == BB - 1);
#pragma unroll
    for (int ei = 0; ei < 16; ++ei) {
        int e = w * 16 + ei;
        float2 ev = *(const float2*)&sm.sY[e * SY_STRIDE + 2 * lane];
        float p = bflo(q01[ei]) * bflo(k01[ei]) * ev.x + bfhi(q01[ei]) * bfhi(k01[ei]) * ev.y;
        p += __shfl_xor(p, 8, 64);
        p += __shfl_xor(p, 4, 64);
        p += __shfl_xor(p, 2, 64);
        p += __shfl_xor(p, 1, 64);
        float av = __expf(fminf(fmaxf(p * INVSQ, -5.f), 5.f));
        if ((lane & 15) == 0) {
            int slot = sSlot[e];
            if (slot < CAP)
                af_buf[((size_t)(b * NN + sSrc[e])) * (CAP * 4) + slot * 4 + h] = av;
            if (isLast) attn_out[(size_t)h * EGc + (e0 + e)] = av;
        }
    }
}

// ============================ kernel 3a: gather-reduce (no LDS, high occupancy) ============================
// Per node: x = (sum af*V) / (sum af + eps) -> packed bf16 pair per lane -> Xg.
// af comes slot-ordered from af_buf: one coalesced dword load per 16-edge chunk,
// independent of the list load. All 4 nodes' list/af loads issue before any V loop.
__global__ __launch_bounds__(256) void gather_kernel(const ushort* __restrict__ Vp,
                                                     const float* __restrict__ af_buf,
                                                     const int* __restrict__ list,
                                                     const int* __restrict__ cnt,
                                                     uint* __restrict__ Xg) {
    int t = threadIdx.x;
    int w = t >> 6, lane = t & 63;
    int wid = blockIdx.x * 4 + w;                // 16384 waves
    size_t n0 = (size_t)wid * 4;                 // 4 nodes per wave
    int b = (int)(n0 >> 14);                     // batch (NN = 16384)
    const uint* Vu = (const uint*)Vp;
    int perm = (lane & 15) * 4 + (lane >> 4);    // afp lane permutation

    int degv = 0;
    if (lane < 4) degv = cnt[n0 + lane];
    int deg[4];
#pragma unroll
    for (int ni = 0; ni < 4; ++ni) {
        int d = __shfl(degv, ni, 64);
        deg[ni] = d < CAP ? d : CAP;
    }

    // issue all list loads (tgt only) for the 4 nodes
    int tv[4];
#pragma unroll
    for (int ni = 0; ni < 4; ++ni) {
        tv[ni] = 0;
        if (lane < deg[ni]) tv[ni] = list[(n0 + ni) * CAP + lane] >> 17;
    }
    // issue all af loads: afp[ni][K] at lane L = af(edge 16K+(L&15), head L>>4), coalesced
    float afp[4][4];
#pragma unroll
    for (int ni = 0; ni < 4; ++ni) {
        const float* ab = af_buf + (n0 + ni) * (CAP * 4);
        afp[ni][0] = ab[perm];
        afp[ni][1] = deg[ni] > 16 ? ab[64 + perm]  : 0.f;
        afp[ni][2] = deg[ni] > 32 ? ab[128 + perm] : 0.f;
        afp[ni][3] = deg[ni] > 48 ? ab[192 + perm] : 0.f;
    }

#pragma unroll
    for (int ni = 0; ni < 4; ++ni) {
        int d = deg[ni];
        float n0v = 0.f, n1v = 0.f, dh = 0.f;
#define FCHUNK(K) \
        if (d > 16 * K) { \
            int lim = d - 16 * K; lim = lim > 16 ? 16 : lim; \
            _Pragma("unroll 8") \
            for (int j2 = 0; j2 < lim; ++j2) { \
                int tgt = __shfl(tv[ni], 16 * K + j2, 64); \
                float af = __shfl(afp[ni][K], (lane & 48) + j2, 64); \
                uint v01 = Vu[((size_t)b * NN + tgt) * 64 + lane]; \
                n0v += af * bflo(v01); n1v += af * bfhi(v01); dh += af; \
            } \
        }
        FCHUNK(0)
        FCHUNK(1)
        FCHUNK(2)
        FCHUNK(3)
#undef FCHUNK
        float inv = 1.f / (dh + 1e-8f);
        uint packed = (uint)f2bf(n0v * inv) | ((uint)f2bf(n1v * inv) << 16);
        Xg[(n0 + ni) * 64 + lane] = packed;
    }
}

// ============================ kernel 3b: fc MFMA + residual + LN ============================
__global__ __launch_bounds__(256) void fc_ln_kernel(const uint* __restrict__ Xg,
                                                    const ushort* __restrict__ WtFC,
                                                    const float* __restrict__ IQ,
                                                    const float* __restrict__ G,
                                                    const float* __restrict__ Bt,
                                                    float* __restrict__ Out) {
    __shared__ SMem sm;
    int t = threadIdx.x;
    size_t r0 = (size_t)blockIdx.x * 64;         // global node-row base
    // stage x tile: 64 rows x 64 uints (bf16 pairs) = 16 KB, plain coalesced copy
    const uint4* X4 = (const uint4*)(Xg + r0 * 64);
#pragma unroll
    for (int i = 0; i < 4; ++i) {
        int f = t + 256 * i;                     // 1024 uint4
        int r = f >> 4, c = f & 15;
        uint4 x = X4[f];
        *(uint4*)&sm.sA[r * SA_STRIDE + c * 8] = x;
    }
    stage_wt(sm, (const uint4*)WtFC, t);
    __syncthreads();
    floatx4 acc[2][4];
    acc_zero(acc);
    mfma_core(sm, t, acc);
    __syncthreads();
    acc_to_sy(sm, t, acc);
    __syncthreads();

    // epilogue: residual + LN, 16 rows per wave
    int w = t >> 6, lane = t & 63;
    float g0 = G[lane], g1 = G[lane + 64];
    float be0 = Bt[lane], be1 = Bt[lane + 64];
    for (int ei = 0; ei < 16; ++ei) {
        int e = w * 16 + ei;
        size_t row = r0 + e;
        float y0 = sm.sY[e * SY_STRIDE + lane]      + IQ[row * 128 + lane];
        float y1 = sm.sY[e * SY_STRIDE + lane + 64] + IQ[row * 128 + lane + 64];
        float s = y0 + y1;
        float qq = y0 * y0 + y1 * y1;
#pragma unroll
        for (int off = 32; off >= 1; off >>= 1) {
            s  += __shfl_xor(s, off, 64);
            qq += __shfl_xor(qq, off, 64);
        }
        float mu = s * (1.f / 128.f);
        float var = qq * (1.f / 128.f) - mu * mu;
        float rstd = rsqrtf(var + 1e-5f);
        Out[row * 128 + lane]      = g0 * (y0 - mu) * rstd + be0;
        Out[row * 128 + lane + 64] = g1 * (y1 - mu) * rstd + be1;
    }
}

// ============================ launch ============================
extern "C" void kernel_launch(void* const* d_in, const int* in_sizes, int n_in,
                              void* d_out, int out_size, void* d_ws, size_t ws_size,
                              hipStream_t stream) {
    const int*   EI  = (const int*)d_in[0];
    const float* EF  = (const float*)d_in[1];
    const float* IQ  = (const float*)d_in[2];
    const float* IK  = (const float*)d_in[3];
    const float* IV  = (const float*)d_in[4];
    const float* WQ  = (const float*)d_in[5];
    const float* WK  = (const float*)d_in[6];
    const float* WV  = (const float*)d_in[7];
    const float* WE  = (const float*)d_in[8];
    const float* WFC = (const float*)d_in[9];
    const float* G   = (const float*)d_in[10];
    const float* Bt  = (const float*)d_in[11];

    char* ws = (char*)d_ws;
    ushort* Qp     = (ushort*)ws;                                     // 16 MB
    ushort* Kp     = (ushort*)(ws + 16777216);                        // 16 MB
    ushort* Vp     = (ushort*)(ws + 2 * 16777216);                    // 16 MB
    ushort* Wt     = (ushort*)(ws + 3 * 16777216);                    // 256 KB reserved (5 x 32 KB used)
    float*  af_buf = (float*) (ws + 3 * 16777216 + 262144);           // 64 MB (B*N*CAP*H f32)
    int*    list   = (int*)   (ws + 3 * 16777216 + 262144 + 67108864);        // 16 MB (B*N*CAP)
    int*    cnt    = (int*)   (ws + 3 * 16777216 + 262144 + 67108864 + 16777216); // 256 KB

    float* out0 = (float*)d_out;
    float* attn_out = out0 + (size_t)BB * NN * 128;                   // (1,H,EG,1)

    hipMemsetAsync(cnt, 0, (size_t)BB * NN * sizeof(int), stream);

    transpose_w<<<5, 256, 0, stream>>>(WQ, WK, WV, WE, WFC, Wt);

    dim3 pg(1024, 3);
    proj_mfma<<<pg, 256, 0, stream>>>(IQ, IK, IV, Wt, Qp, Kp, Vp);

    edge_kernel<<<BB * (EGc / 64), 256, 0, stream>>>(EI, EF, Wt + 3 * 16384,
                                                     Qp, Kp, af_buf, list, cnt, attn_out);

    // Qp is dead after edge_kernel -> reuse as packed bf16 x-row buffer
    uint* Xg = (uint*)Qp;
    gather_kernel<<<4096, 256, 0, stream>>>(Vp, af_buf, list, cnt, Xg);

    fc_ln_kernel<<<1024, 256, 0, stream>>>(Xg, Wt + 4 * 16384, IQ, G, Bt, out0);
}

// Round 4
// 558.636 us; speedup vs baseline: 1.0521x; 1.0521x over previous
//
#include <hip/hip_runtime.h>

// Problem constants
#define BB 4
#define NN 16384
#define EGc 131072
#define CAP 64
#define INVSQ 0.17677669529663687f

typedef unsigned int uint;
typedef unsigned short ushort;
typedef short short8 __attribute__((ext_vector_type(8)));    // 8 bf16 = 4 VGPR (MFMA A/B frag)
typedef float floatx4 __attribute__((ext_vector_type(4)));   // MFMA C/D frag

__device__ __forceinline__ float bflo(uint u) { return __uint_as_float(u << 16); }
__device__ __forceinline__ float bfhi(uint u) { return __uint_as_float(u & 0xffff0000u); }
__device__ __forceinline__ ushort f2bf(float f) {
    uint u = __float_as_uint(f);
    u += 0x7fffu + ((u >> 16) & 1u);   // RTNE
    return (ushort)(u >> 16);
}

#define SA_STRIDE 136
#define SW_STRIDE 136
#define SY_STRIDE 132
struct __align__(16) SMem {
    union {
        struct {
            ushort sA[64 * SA_STRIDE];    // 17408 B
            ushort sW[128 * SW_STRIDE];   // 34816 B
        };
        float  sY[64 * SY_STRIDE];        // 33792 B
        ushort sOut[64 * 128];            // 16384 B (proj bf16 out-stage)
    };
};

// ---- staging (512-thread): X rows (f32 -> bf16, row-major) ----
__device__ __forceinline__ void stage_x512(SMem& sm, const float4* __restrict__ X4,
                                           size_t r0, int t) {
#pragma unroll
    for (int i = 0; i < 4; ++i) {
        int f = t + 512 * i;              // 2048 float4 = 64 rows x 32
        int r = f >> 5, c4 = f & 31;
        float4 x = X4[(r0 + r) * 32 + c4];
        ushort4 h;
        h.x = f2bf(x.x); h.y = f2bf(x.y); h.z = f2bf(x.z); h.w = f2bf(x.w);
        *(ushort4*)&sm.sA[r * SA_STRIDE + c4 * 4] = h;
    }
}

// ---- staging (512-thread): pre-transposed bf16 weight -> LDS padded ----
__device__ __forceinline__ void stage_wt512(SMem& sm, const uint4* __restrict__ Wt4, int t) {
#pragma unroll
    for (int i = 0; i < 4; ++i) {
        int f = t + 512 * i;              // 2048 uint4; c = row, kc = 8-elt chunk
        int c = f >> 4, kc = f & 15;
        uint4 w = Wt4[f];
        *(uint4*)&sm.sW[c * SW_STRIDE + kc * 8] = w;
    }
}

// ---- MFMA core (8 waves): 64x128 tile, K=128. Wave = 16 rows x 64 cols (1x4 16x16) ----
__device__ __forceinline__ void mfma_core512(const SMem& sm, int t, floatx4 (&acc)[4]) {
    int lane = t & 63, w = t >> 6;        // w in 0..7
    int wr = (w >> 1) * 16, wc = (w & 1) * 64;
    int m = lane & 15, q = lane >> 4;
#pragma unroll
    for (int ks = 0; ks < 4; ++ks) {
        int k = ks * 32 + q * 8;
        short8 a = *(const short8*)&sm.sA[(wr + m) * SA_STRIDE + k];
#pragma unroll
        for (int j = 0; j < 4; ++j) {
            short8 b = *(const short8*)&sm.sW[(wc + j * 16 + m) * SW_STRIDE + k];
            acc[j] = __builtin_amdgcn_mfma_f32_16x16x32_bf16(a, b, acc[j], 0, 0, 0);
        }
    }
}

__device__ __forceinline__ void acc_zero4(floatx4 (&acc)[4]) {
    floatx4 z = {0.f, 0.f, 0.f, 0.f};
#pragma unroll
    for (int j = 0; j < 4; ++j) acc[j] = z;
}

// C/D layout: col = lane&15, row = (lane>>4)*4 + reg   [m89-verified]
__device__ __forceinline__ void acc_to_sy512(SMem& sm, int t, const floatx4 (&acc)[4]) {
    int lane = t & 63, w = t >> 6;
    int wr = (w >> 1) * 16, wc = (w & 1) * 64;
    int m = lane & 15, q = lane >> 4;
#pragma unroll
    for (int j = 0; j < 4; ++j)
#pragma unroll
        for (int r = 0; r < 4; ++r)
            sm.sY[(wr + q * 4 + r) * SY_STRIDE + wc + j * 16 + m] = acc[j][r];
}

// ============================ kernel 0: weight pre-transpose ============================
__global__ __launch_bounds__(256) void transpose_w(const float* __restrict__ W0,
                                                   const float* __restrict__ W1,
                                                   const float* __restrict__ W2,
                                                   const float* __restrict__ W3,
                                                   const float* __restrict__ W4,
                                                   ushort* __restrict__ Wt) {
    __shared__ ushort sT[128 * 136];
    int bi = blockIdx.x;
    const float* W = bi == 0 ? W0 : bi == 1 ? W1 : bi == 2 ? W2 : bi == 3 ? W3 : W4;
    int t = threadIdx.x;
    const float4* Wp = (const float4*)W;
#pragma unroll
    for (int i = 0; i < 16; ++i) {
        int f = t + 256 * i;
        int d = f >> 5, c4 = f & 31;
        float4 w = Wp[f];
        sT[(c4 * 4 + 0) * 136 + d] = f2bf(w.x);
        sT[(c4 * 4 + 1) * 136 + d] = f2bf(w.y);
        sT[(c4 * 4 + 2) * 136 + d] = f2bf(w.z);
        sT[(c4 * 4 + 3) * 136 + d] = f2bf(w.w);
    }
    __syncthreads();
    uint4* out = (uint4*)(Wt + (size_t)bi * 16384);
#pragma unroll
    for (int i = 0; i < 8; ++i) {
        int f = t + 256 * i;
        int c = f >> 4, kc = f & 15;
        out[f] = *(const uint4*)&sT[c * 136 + kc * 8];
    }
}

// ============================ kernel 1: fused Q/K/V projection (512 thr, 24 waves/CU) ============
__global__ __launch_bounds__(512, 6) void proj_mfma(const float* __restrict__ IQ,
                                                    const float* __restrict__ IK,
                                                    const float* __restrict__ IV,
                                                    const ushort* __restrict__ WtAll,
                                                    ushort* __restrict__ Qp,
                                                    ushort* __restrict__ Kp,
                                                    ushort* __restrict__ Vp) {
    __shared__ SMem sm;
    int t = threadIdx.x;
    const float* X; const ushort* Wt; ushort* Y;
    if (blockIdx.y == 0)      { X = IQ; Wt = WtAll;         Y = Qp; }
    else if (blockIdx.y == 1) { X = IK; Wt = WtAll + 16384; Y = Kp; }
    else                      { X = IV; Wt = WtAll + 32768; Y = Vp; }
    size_t r0 = (size_t)blockIdx.x * 64;
    stage_x512(sm, (const float4*)X, r0, t);
    stage_wt512(sm, (const uint4*)Wt, t);
    __syncthreads();
    floatx4 acc[4];
    acc_zero4(acc);
    mfma_core512(sm, t, acc);
    __syncthreads();
    {
        int lane = t & 63, w = t >> 6;
        int wr = (w >> 1) * 16, wc = (w & 1) * 64;
        int m = lane & 15, q = lane >> 4;
#pragma unroll
        for (int j = 0; j < 4; ++j)
#pragma unroll
            for (int r = 0; r < 4; ++r)
                sm.sOut[(wr + q * 4 + r) * 128 + wc + j * 16 + m] = f2bf(acc[j][r]);
    }
    __syncthreads();
    uint4* Y4 = (uint4*)Y;
#pragma unroll
    for (int i = 0; i < 2; ++i) {
        int f = t + 512 * i;                     // 1024 uint4
        Y4[r0 * 16 + f] = *(const uint4*)&sm.sOut[f * 8];
    }
}

// ============================ kernel 2: edges (512 thr, 24 waves/CU) ============================
// E = EF @ W_E (MFMA) + score/exp -> aArr[b][e][4] + append edge to src bucket.
__global__ __launch_bounds__(512, 6) void edge_kernel(const int* __restrict__ EI,
                                                      const float* __restrict__ EF,
                                                      const ushort* __restrict__ WtE,
                                                      const ushort* __restrict__ Qp,
                                                      const ushort* __restrict__ Kp,
                                                      float* __restrict__ aArr,
                                                      int* __restrict__ list,
                                                      int* __restrict__ cnt,
                                                      float* __restrict__ attn_out) {
    __shared__ SMem sm;
    int t = threadIdx.x;
    int b = blockIdx.x >> 11;            // 2048 tiles per batch
    int tile = blockIdx.x & 2047;
    int e0 = tile * 64;
    int w = t >> 6, lane = t & 63;

    // --- parallel list append: one thread per edge; payload packs (tgt<<17)|ge ---
    if (t < 64) {
        int ge = e0 + t;
        int src = EI[(size_t)b * 2 * EGc + ge];
        int tgt = EI[(size_t)b * 2 * EGc + EGc + ge];
        int slot = atomicAdd(&cnt[b * NN + src], 1);
        if (slot < CAP) list[((size_t)(b * NN + src)) * CAP + slot] = (tgt << 17) | ge;
    }

    // --- prefetch Q/K rows for this wave's 8 edges (16 loads in flight) ---
    int e8 = w * 8 + (lane & 7);
    int srcv = EI[(size_t)b * 2 * EGc + e0 + e8];
    int tgtv = EI[(size_t)b * 2 * EGc + EGc + e0 + e8];
    const uint* Qu = (const uint*)Qp;
    const uint* Ku = (const uint*)Kp;
    uint q01[8], k01[8];
#pragma unroll
    for (int ei = 0; ei < 8; ++ei) {
        int s = __shfl(srcv, ei, 8);
        int g = __shfl(tgtv, ei, 8);
        q01[ei] = Qu[((size_t)b * NN + s) * 64 + lane];
        k01[ei] = Ku[((size_t)b * NN + g) * 64 + lane];
    }

    stage_x512(sm, (const float4*)EF, (size_t)b * EGc + e0, t);
    stage_wt512(sm, (const uint4*)WtE, t);
    __syncthreads();
    floatx4 acc[4];
    acc_zero4(acc);
    mfma_core512(sm, t, acc);
    __syncthreads();
    acc_to_sy512(sm, t, acc);            // sY[e][c] = E values (f32)
    __syncthreads();

    int h = lane >> 4;                   // head of channels 2*lane, 2*lane+1
    bool isLast = (b == BB - 1);
#pragma unroll
    for (int ei = 0; ei < 8; ++ei) {
        int e = w * 8 + ei;
        float2 ev = *(const float2*)&sm.sY[e * SY_STRIDE + 2 * lane];
        float p = bflo(q01[ei]) * bflo(k01[ei]) * ev.x + bfhi(q01[ei]) * bfhi(k01[ei]) * ev.y;
        p += __shfl_xor(p, 8, 64);
        p += __shfl_xor(p, 4, 64);
        p += __shfl_xor(p, 2, 64);
        p += __shfl_xor(p, 1, 64);
        float av = __expf(fminf(fmaxf(p * INVSQ, -5.f), 5.f));
        int ge = e0 + e;                 // edge id within batch
        if ((lane & 15) == 0) {
            aArr[((size_t)b * EGc + ge) * 4 + h] = av;
            if (isLast) attn_out[(size_t)h * EGc + ge] = av;
        }
    }
}

// ============================ kernel 3a: gather-reduce (no LDS, high occupancy) ============================
// Per node: x = (sum af*V) / (sum af + eps) -> packed bf16 pair per lane -> Xg.
__global__ __launch_bounds__(256) void gather_kernel(const ushort* __restrict__ Vp,
                                                     const float* __restrict__ aArr,
                                                     const int* __restrict__ list,
                                                     const int* __restrict__ cnt,
                                                     uint* __restrict__ Xg) {
    int t = threadIdx.x;
    int w = t >> 6, lane = t & 63;
    int wid = blockIdx.x * 4 + w;                // 16384 waves
    size_t n0 = (size_t)wid * 4;                 // 4 nodes per wave
    int b = (int)(n0 >> 14);                     // batch (NN = 16384)
    int h = lane >> 4;                           // head of channels 2*lane, 2*lane+1
    const uint* Vu = (const uint*)Vp;
    const float* aBase = aArr + (size_t)b * EGc * 4;

    int degv = 0;
    if (lane < 4) degv = cnt[n0 + lane];

    for (int ni = 0; ni < 4; ++ni) {
        size_t grow = n0 + ni;
        int deg = __shfl(degv, ni, 64);
        deg = deg < CAP ? deg : CAP;
        // prefetch this node's whole edge list (packed tgt|e) with a single gather
        int le = 0, tv = 0;
        if (lane < deg) {
            int pk = list[grow * CAP + lane];
            le = pk & 0x1FFFF;
            tv = pk >> 17;
        }
        // af prefetch: afpK at lane L = af(edge K*16+(L&15), head L>>4)
        float afp0, afp1 = 0.f, afp2 = 0.f, afp3 = 0.f;
        {
            int m0 = __shfl(le, lane & 15, 64);
            afp0 = aBase[(size_t)m0 * 4 + h];
            if (deg > 16) { int m1 = __shfl(le, 16 + (lane & 15), 64); afp1 = aBase[(size_t)m1 * 4 + h]; }
            if (deg > 32) { int m2 = __shfl(le, 32 + (lane & 15), 64); afp2 = aBase[(size_t)m2 * 4 + h]; }
            if (deg > 48) { int m3 = __shfl(le, 48 + (lane & 15), 64); afp3 = aBase[(size_t)m3 * 4 + h]; }
        }
        float n0v = 0.f, n1v = 0.f, dh = 0.f;
#define FCHUNK(K, AFP) \
        if (deg > 16 * K) { \
            int lim = deg - 16 * K; lim = lim > 16 ? 16 : lim; \
            _Pragma("unroll 8") \
            for (int j2 = 0; j2 < lim; ++j2) { \
                int tgt = __shfl(tv, 16 * K + j2, 64); \
                float af = __shfl(AFP, (lane & 48) + j2, 64); \
                uint v01 = Vu[((size_t)b * NN + tgt) * 64 + lane]; \
                n0v += af * bflo(v01); n1v += af * bfhi(v01); dh += af; \
            } \
        }
        FCHUNK(0, afp0)
        FCHUNK(1, afp1)
        FCHUNK(2, afp2)
        FCHUNK(3, afp3)
#undef FCHUNK
        float inv = 1.f / (dh + 1e-8f);
        uint packed = (uint)f2bf(n0v * inv) | ((uint)f2bf(n1v * inv) << 16);
        Xg[grow * 64 + lane] = packed;
    }
}

// ============================ kernel 3b: fc MFMA + residual + LN (512 thr) ============================
__global__ __launch_bounds__(512, 6) void fc_ln_kernel(const uint* __restrict__ Xg,
                                                       const ushort* __restrict__ WtFC,
                                                       const float* __restrict__ IQ,
                                                       const float* __restrict__ G,
                                                       const float* __restrict__ Bt,
                                                       float* __restrict__ Out) {
    __shared__ SMem sm;
    int t = threadIdx.x;
    size_t r0 = (size_t)blockIdx.x * 64;         // global node-row base
    // stage x tile: 64 rows x 64 uints (bf16 pairs) = 16 KB, plain coalesced copy
    const uint4* X4 = (const uint4*)(Xg + r0 * 64);
#pragma unroll
    for (int i = 0; i < 2; ++i) {
        int f = t + 512 * i;                     // 1024 uint4
        int r = f >> 4, c = f & 15;
        uint4 x = X4[f];
        *(uint4*)&sm.sA[r * SA_STRIDE + c * 8] = x;
    }
    stage_wt512(sm, (const uint4*)WtFC, t);
    __syncthreads();
    floatx4 acc[4];
    acc_zero4(acc);
    mfma_core512(sm, t, acc);
    __syncthreads();
    acc_to_sy512(sm, t, acc);
    __syncthreads();

    // epilogue: residual + LN, 8 rows per wave
    int w = t >> 6, lane = t & 63;
    float g0 = G[lane], g1 = G[lane + 64];
    float be0 = Bt[lane], be1 = Bt[lane + 64];
    for (int ei = 0; ei < 8; ++ei) {
        int e = w * 8 + ei;
        size_t row = r0 + e;
        float y0 = sm.sY[e * SY_STRIDE + lane]      + IQ[row * 128 + lane];
        float y1 = sm.sY[e * SY_STRIDE + lane + 64] + IQ[row * 128 + lane + 64];
        float s = y0 + y1;
        float qq = y0 * y0 + y1 * y1;
#pragma unroll
        for (int off = 32; off >= 1; off >>= 1) {
            s  += __shfl_xor(s, off, 64);
            qq += __shfl_xor(qq, off, 64);
        }
        float mu = s * (1.f / 128.f);
        float var = qq * (1.f / 128.f) - mu * mu;
        float rstd = rsqrtf(var + 1e-5f);
        Out[row * 128 + lane]      = g0 * (y0 - mu) * rstd + be0;
        Out[row * 128 + lane + 64] = g1 * (y1 - mu) * rstd + be1;
    }
}

// ============================ launch ============================
extern "C" void kernel_launch(void* const* d_in, const int* in_sizes, int n_in,
                              void* d_out, int out_size, void* d_ws, size_t ws_size,
                              hipStream_t stream) {
    const int*   EI  = (const int*)d_in[0];
    const float* EF  = (const float*)d_in[1];
    const float* IQ  = (const float*)d_in[2];
    const float* IK  = (const float*)d_in[3];
    const float* IV  = (const float*)d_in[4];
    const float* WQ  = (const float*)d_in[5];
    const float* WK  = (const float*)d_in[6];
    const float* WV  = (const float*)d_in[7];
    const float* WE  = (const float*)d_in[8];
    const float* WFC = (const float*)d_in[9];
    const float* G   = (const float*)d_in[10];
    const float* Bt  = (const float*)d_in[11];

    char* ws = (char*)d_ws;
    ushort* Qp   = (ushort*)ws;                                  // 16 MB
    ushort* Kp   = (ushort*)(ws + 16777216);                     // 16 MB
    ushort* Vp   = (ushort*)(ws + 2 * 16777216);                 // 16 MB
    ushort* Wt   = (ushort*)(ws + 3 * 16777216);                 // 160 KB (5 x 32 KB)
    float*  aArr = (float*) (ws + 3 * 16777216 + 262144);        // 8 MB   (B*EG*4)
    int*    list = (int*)   (ws + 3 * 16777216 + 262144 + 8388608);   // 16 MB (B*N*CAP)
    int*    cnt  = (int*)   (ws + 4 * 16777216 + 262144 + 8388608);   // 256 KB

    float* out0 = (float*)d_out;
    float* attn_out = out0 + (size_t)BB * NN * 128;              // (1,H,EG,1)

    hipMemsetAsync(cnt, 0, (size_t)BB * NN * sizeof(int), stream);

    transpose_w<<<5, 256, 0, stream>>>(WQ, WK, WV, WE, WFC, Wt);

    dim3 pg(1024, 3);
    proj_mfma<<<pg, 512, 0, stream>>>(IQ, IK, IV, Wt, Qp, Kp, Vp);

    edge_kernel<<<BB * (EGc / 64), 512, 0, stream>>>(EI, EF, Wt + 3 * 16384,
                                                     Qp, Kp, aArr, list, cnt, attn_out);

    // Qp is dead after edge_kernel -> reuse as packed bf16 x-row buffer
    uint* Xg = (uint*)Qp;
    gather_kernel<<<4096, 256, 0, stream>>>(Vp, aArr, list, cnt, Xg);

    fc_ln_kernel<<<1024, 512, 0, stream>>>(Xg, Wt + 4 * 16384, IQ, G, Bt, out0);
}